// Round 3
// baseline (305.818 us; speedup 1.0000x reference)
//
#include <hip/hip_runtime.h>

// Problem constants (B=4, S=4096, D_MODEL=1024, H*Dk=H*Dv=1024)
#define M_TOT 16384
#define DM    1024

typedef unsigned short ushort_t;
typedef __bf16 bf16x8 __attribute__((ext_vector_type(8)));
typedef float  f32x16 __attribute__((ext_vector_type(16)));

__device__ __forceinline__ ushort_t f32_to_bf16(float f) {
    union { float f; unsigned u; } v; v.f = f;
    unsigned u = v.u;
    return (ushort_t)((u + 0x7fffu + ((u >> 16) & 1u)) >> 16);   // RNE
}
__device__ __forceinline__ float bf16_to_f32(ushort_t h) {
    union { unsigned u; float f; } v; v.u = ((unsigned)h) << 16;
    return v.f;
}

// async global->LDS, 16B per lane; LDS dest is wave-uniform base + lane*16
__device__ __forceinline__ void gload16(const ushort_t* g, ushort_t* l) {
    __builtin_amdgcn_global_load_lds(
        (const __attribute__((address_space(1))) unsigned int*)g,
        (__attribute__((address_space(3))) unsigned int*)l,
        16, 0, 0);
}

// ---------------- fused fp32 -> bf16 conversion ----------------
// x -> xb; Wv/Wg -> wcat with 32-row interleave: v rows p*64+r, g rows
// p*64+32+r (r<32). A 32-col MFMA B-frag is then pure-V or pure-g, and the
// V-frag / g-frag pair shares lanes+rows exactly -> lane-local silu fuse.
__global__ __launch_bounds__(256) void cvt_all(const float* __restrict__ x,
                                               const float* __restrict__ wv,
                                               const float* __restrict__ wg,
                                               const float* __restrict__ wo,
                                               ushort_t* __restrict__ xb,
                                               ushort_t* __restrict__ wcat,
                                               ushort_t* __restrict__ wob) {
    const long NX = (long)M_TOT * DM / 4, NW = (long)DM * DM / 4;
    long i = (long)blockIdx.x * 256 + threadIdx.x;     // float4 index
    const float* src; ushort_t* dst; long so, di;
    if (i < NX) {
        src = x; so = i; dst = xb; di = i;
    } else if (i < NX + NW) {
        long j = i - NX; src = wv; so = j;
        int row = (int)(j >> 8), c4 = (int)(j & 255);
        int orow = ((row >> 5) << 6) | (row & 31);
        dst = wcat; di = (long)orow * 256 + c4;
    } else if (i < NX + 2 * NW) {
        long j = i - NX - NW; src = wg; so = j;
        int row = (int)(j >> 8), c4 = (int)(j & 255);
        int orow = ((row >> 5) << 6) | 32 | (row & 31);
        dst = wcat; di = (long)orow * 256 + c4;
    } else {
        long j = i - NX - 2 * NW; src = wo; so = j; dst = wob; di = j;
    }
    const float4 v = ((const float4*)src)[so];
    ushort4 o;
    o.x = f32_to_bf16(v.x); o.y = f32_to_bf16(v.y);
    o.z = f32_to_bf16(v.z); o.w = f32_to_bf16(v.w);
    ((ushort4*)dst)[di] = o;
}

// ---------------- 256x128 2-resident-block pipelined GEMM ----------------
// BM=256, BN=128, 256 threads (4 waves, 2M x 2N), per-wave 128x64 via
// mfma_f32_32x32x16_bf16, acc[4][2] f32x16.  K split into 32 units of 32.
// LDS 72 KB = ring of 3 unit-slots (A 16KB + B 8KB), fragment-tiled 1KB
// lane-linear frags (conflict-free, linear gload_lds dest). Stage-ahead 2.
// ONE barrier per unit; counted vmcnt(6) (never 0 until drain). 72KB -> TWO
// blocks co-resident per CU: inter-block overlap hides LDS/latency phases
// (the mechanism behind r0's 790 TF at 3 blocks/CU; r1/r2's 1-block
// schedules all plateaued at the same 790 regardless of interleave).
// A-frag layout (32x32x16): lane l holds row (l&31), k-half (l>>5)*8.
// C/D layout (m74/m101): col=lane&31, row=(reg&3)+8*(reg>>2)+4*(lane>>5).
// EPI=0: acc[i][0]=V, acc[i][1]=g (wcat interleave) -> gated bf16 [M,1024]
// EPI=1: +bf16 residual -> pre bf16 [M,1024] (in-place over Xb is safe)
template<int EPI>
__global__ __launch_bounds__(256, 2) void gemm2b(
    const ushort_t* __restrict__ A,
    const ushort_t* __restrict__ Bm,
    const ushort_t* __restrict__ Xb,
    ushort_t* __restrict__ out,
    int nbs)                          // log2(n-blocks per XCD stripe)
{
    extern __shared__ ushort_t lds[];   // 36864 ushorts = 72 KB

    const int flat = blockIdx.x;
    const int xcd  = flat & 7;
    const int ii   = flat >> 3;
    const int m0   = ((xcd << 3) + (ii >> nbs)) << 8;            // 256-row blocks
    const int n0   = (ii & ((1 << nbs) - 1)) << 7;               // 128-col blocks

    const int tid  = threadIdx.x;
    const int w    = tid >> 6;         // wave 0..3
    const int l    = tid & 63;
    const int wm   = w >> 1;           // 0..1 (M)
    const int wn   = w & 1;            // 0..1 (N)

    f32x16 acc[4][2];
#pragma unroll
    for (int i = 0; i < 4; ++i)
#pragma unroll
        for (int j = 0; j < 2; ++j) acc[i][j] = (f32x16)(0.f);

    // staging: wave w owns A frags q=w*4..w*4+3, B frags q=w*2..w*2+1.
    // frag q=(f,kh): rows base+32f+(l&31), k = ko + kh*16 + (l>>5)*8.
    long gsrcA[4], gsrcB[2];
#pragma unroll
    for (int t = 0; t < 4; ++t) {
        const int q = w * 4 + t, f = q >> 1, kh = q & 1;
        gsrcA[t] = (long)(m0 + (f << 5) + (l & 31)) * DM + (kh << 4) + ((l >> 5) << 3);
    }
#pragma unroll
    for (int t = 0; t < 2; ++t) {
        const int q = w * 2 + t, f = q >> 1, kh = q & 1;
        gsrcB[t] = (long)(n0 + (f << 5) + (l & 31)) * DM + (kh << 4) + ((l >> 5) << 3);
    }

    auto stage = [&](int u, int s) {   // 6 gload16 per thread per unit
        const int ko = u * 32;
        const int aBase = s * 8192 + l * 8;
        const int bBase = 24576 + s * 4096 + l * 8;
#pragma unroll
        for (int t = 0; t < 4; ++t)
            gload16(A + gsrcA[t] + ko, lds + aBase + (w * 4 + t) * 512);
#pragma unroll
        for (int t = 0; t < 2; ++t)
            gload16(Bm + gsrcB[t] + ko, lds + bBase + (w * 2 + t) * 512);
    };

    // fragment read offsets (slot-relative, ushorts)
    int rdA[4][2], rdB[2][2];
#pragma unroll
    for (int i = 0; i < 4; ++i)
#pragma unroll
        for (int kh = 0; kh < 2; ++kh)
            rdA[i][kh] = ((wm * 4 + i) * 2 + kh) * 512 + l * 8;
#pragma unroll
    for (int j = 0; j < 2; ++j)
#pragma unroll
        for (int kh = 0; kh < 2; ++kh)
            rdB[j][kh] = 24576 + ((wn * 2 + j) * 2 + kh) * 512 + l * 8;

    // prologue: units 0,1 in flight; wait unit 0 (6 oldest of 12)
    stage(0, 0); stage(1, 1);
    asm volatile("s_waitcnt vmcnt(6)" ::: "memory");
    __builtin_amdgcn_s_barrier();

    int sC = 0, sS = 2;
    for (int u = 0; u < 32; ++u) {
        const int ab = sC * 8192;
        const int bb = sC * 4096;
        bf16x8 af[4][2], bf[2][2];
#pragma unroll
        for (int j = 0; j < 2; ++j)
#pragma unroll
            for (int kh = 0; kh < 2; ++kh)
                bf[j][kh] = *(const bf16x8*)(lds + bb + rdB[j][kh]);
#pragma unroll
        for (int i = 0; i < 4; ++i)
#pragma unroll
            for (int kh = 0; kh < 2; ++kh)
                af[i][kh] = *(const bf16x8*)(lds + ab + rdA[i][kh]);

        if (u < 30) stage(u + 2, sS);
        // drain own ds_reads pre-barrier (other resident block covers the wait);
        // counted vmcnt: unit u+1's 6 loads retired, slots u+2.. stay in flight
        asm volatile("s_waitcnt lgkmcnt(0)" ::: "memory");
        if (u < 30)       { asm volatile("s_waitcnt vmcnt(6)" ::: "memory"); }
        else if (u == 30) { asm volatile("s_waitcnt vmcnt(0)" ::: "memory"); }
        __builtin_amdgcn_sched_barrier(0);
        __builtin_amdgcn_s_barrier();
        __builtin_amdgcn_sched_barrier(0);

        __builtin_amdgcn_s_setprio(1);
#pragma unroll
        for (int kh = 0; kh < 2; ++kh)
#pragma unroll
            for (int j = 0; j < 2; ++j)
#pragma unroll
                for (int i = 0; i < 4; ++i)
                    acc[i][j] = __builtin_amdgcn_mfma_f32_32x32x16_bf16(
                        af[i][kh], bf[j][kh], acc[i][j], 0, 0, 0);
        __builtin_amdgcn_s_setprio(0);
        __builtin_amdgcn_sched_barrier(0);

        if (++sC == 3) sC = 0;
        if (++sS == 3) sS = 0;
    }

    // epilogue; C/D: col=lane&31, row=(r&3)+8*(r>>2)+4*(l>>5)
    const int rowb = m0 + wm * 128 + ((l >> 5) << 2);
    if (EPI == 0) {
        const int colv = ((n0 + wn * 64) >> 1) + (l & 31);   // v-col (interleave-32)
#pragma unroll
        for (int i = 0; i < 4; ++i)
#pragma unroll
            for (int r = 0; r < 16; ++r) {
                const int row = rowb + i * 32 + (r & 3) + ((r >> 2) << 3);
                float v = acc[i][0][r];
                float g = acc[i][1][r];
                float gate = g / (1.0f + __expf(-g));        // silu
                out[(long)row * DM + colv] = f32_to_bf16(v * gate);
            }
    } else {
        const int colb = n0 + wn * 64 + (l & 31);
#pragma unroll
        for (int i = 0; i < 4; ++i)
#pragma unroll
            for (int j = 0; j < 2; ++j) {
                const int col = colb + j * 32;
#pragma unroll
                for (int r = 0; r < 16; ++r) {
                    const int row = rowb + i * 32 + (r & 3) + ((r >> 2) << 3);
                    float pre = acc[i][j][r] + bf16_to_f32(Xb[(long)row * DM + col]);
                    out[(long)row * DM + col] = f32_to_bf16(pre);
                }
            }
    }
}

// ---------------- LayerNorm over rows of 1024 ----------------
__global__ __launch_bounds__(256) void ln_rows(const ushort_t* __restrict__ pre,
                                               const float* __restrict__ gamma,
                                               const float* __restrict__ beta,
                                               float* __restrict__ out)
{
    const int row = blockIdx.x;
    const int tid = threadIdx.x;
    const int wave = tid >> 6, lane = tid & 63;

    ushort4 u = ((const ushort4*)(pre + row * DM))[tid];
    float p0 = bf16_to_f32(u.x), p1 = bf16_to_f32(u.y);
    float p2 = bf16_to_f32(u.z), p3 = bf16_to_f32(u.w);

    float s  = p0 + p1 + p2 + p3;
    float ss = p0 * p0 + p1 * p1 + p2 * p2 + p3 * p3;
#pragma unroll
    for (int off = 32; off > 0; off >>= 1) {
        s  += __shfl_down(s, off);
        ss += __shfl_down(ss, off);
    }
    __shared__ float red[8];
    __shared__ float mb[2];
    if (lane == 0) { red[wave] = s; red[4 + wave] = ss; }
    __syncthreads();
    if (tid == 0) {
        float S  = red[0] + red[1] + red[2] + red[3];
        float SS = red[4] + red[5] + red[6] + red[7];
        float mean = S * (1.0f / 1024.0f);
        float var  = SS * (1.0f / 1024.0f) - mean * mean;
        mb[0] = mean;
        mb[1] = rsqrtf(var + 1e-5f);
    }
    __syncthreads();
    const float mean = mb[0], rs = mb[1];

    float4 gm = ((const float4*)gamma)[tid];
    float4 bt = ((const float4*)beta)[tid];
    float4 o;
    o.x = (p0 - mean) * rs * gm.x + bt.x;
    o.y = (p1 - mean) * rs * gm.y + bt.y;
    o.z = (p2 - mean) * rs * gm.z + bt.z;
    o.w = (p3 - mean) * rs * gm.w + bt.w;
    ((float4*)(out + row * DM))[tid] = o;
}

// ---------------- launch ----------------
extern "C" void kernel_launch(void* const* d_in, const int* in_sizes, int n_in,
                              void* d_out, int out_size, void* d_ws, size_t ws_size,
                              hipStream_t stream) {
    // setup_inputs order: x, W_Q, W_K, W_V, W_g, W_alpha, W_O, ln_gamma, ln_beta
    const float* x     = (const float*)d_in[0];
    const float* WV    = (const float*)d_in[3];
    const float* WG    = (const float*)d_in[4];
    const float* WO    = (const float*)d_in[6];
    const float* gamma = (const float*)d_in[7];
    const float* beta  = (const float*)d_in[8];
    float* out = (float*)d_out;

    // ws layout: [0,32MB): x_bf16 (aliased as pre) | [32,64MB): gated
    //            [64,68MB): wcat (2048x1024 interleaved-32) | [68,70MB): wob
    char* ws = (char*)d_ws;
    ushort_t* xb    = (ushort_t*)ws;
    ushort_t* gated = (ushort_t*)(ws + (size_t)M_TOT * DM * 2);
    ushort_t* wcat  = (ushort_t*)(ws + (size_t)M_TOT * DM * 4);
    ushort_t* wob   = (ushort_t*)(ws + (size_t)M_TOT * DM * 4 + (size_t)2 * DM * DM * 2);
    ushort_t* pre   = xb;  // alias: in-place residual+store in gemm2b<1>

    static bool attr_set = false;
    if (!attr_set) {
        hipFuncSetAttribute((const void*)&gemm2b<0>,
                            hipFuncAttributeMaxDynamicSharedMemorySize, 73728);
        hipFuncSetAttribute((const void*)&gemm2b<1>,
                            hipFuncAttributeMaxDynamicSharedMemorySize, 73728);
        attr_set = true;
    }

    const int nCvt = (M_TOT * DM + 3 * DM * DM) / 4 / 256;
    cvt_all<<<nCvt, 256, 0, stream>>>(x, WV, WG, WO, xb, wcat, wob);

    // V&g cat-GEMM: M=16384 (64 m-blocks), N_cat=2048 (16 n-blocks) -> 1024
    gemm2b<0><<<1024, 256, 73728, stream>>>(xb, wcat, nullptr, gated, 4);
    // O-proj: M=16384 (64), N=1024 (8 n-blocks) -> 512
    gemm2b<1><<<512, 256, 73728, stream>>>(gated, wob, xb, pre, 3);

    ln_rows<<<M_TOT, 256, 0, stream>>>(pre, gamma, beta, out);
}

// Round 4
// 270.442 us; speedup vs baseline: 1.1308x; 1.1308x over previous
//
#include <hip/hip_runtime.h>

// Problem constants (B=4, S=4096, D_MODEL=1024, H*Dk=H*Dv=1024)
#define M_TOT 16384
#define DM    1024

typedef unsigned short ushort_t;
typedef __bf16 bf16x8 __attribute__((ext_vector_type(8)));
typedef float  f32x4  __attribute__((ext_vector_type(4)));

__device__ __forceinline__ ushort_t f32_to_bf16(float f) {
    union { float f; unsigned u; } v; v.f = f;
    unsigned u = v.u;
    return (ushort_t)((u + 0x7fffu + ((u >> 16) & 1u)) >> 16);   // RNE
}
__device__ __forceinline__ float bf16_to_f32(ushort_t h) {
    union { unsigned u; float f; } v; v.u = ((unsigned)h) << 16;
    return v.f;
}

// async global->LDS, 16B per lane; LDS dest is wave-uniform base + lane*16
__device__ __forceinline__ void gload16(const ushort_t* g, ushort_t* l) {
    __builtin_amdgcn_global_load_lds(
        (const __attribute__((address_space(1))) unsigned int*)g,
        (__attribute__((address_space(3))) unsigned int*)l,
        16, 0, 0);
}

// ---------------- fused fp32 -> bf16 conversion ----------------
// x -> xb; Wv/Wg -> wcat with 16-row interleave (v rows p*32+r, g rows p*32+16+r)
// so a 256-col GEMM tile pairs v/g 16-col fragments within one wave; Wo -> wob.
__global__ __launch_bounds__(256) void cvt_all(const float* __restrict__ x,
                                               const float* __restrict__ wv,
                                               const float* __restrict__ wg,
                                               const float* __restrict__ wo,
                                               ushort_t* __restrict__ xb,
                                               ushort_t* __restrict__ wcat,
                                               ushort_t* __restrict__ wob) {
    const long NX = (long)M_TOT * DM / 4, NW = (long)DM * DM / 4;
    long i = (long)blockIdx.x * 256 + threadIdx.x;     // float4 index
    const float* src; ushort_t* dst; long so, di;
    if (i < NX) {
        src = x; so = i; dst = xb; di = i;
    } else if (i < NX + NW) {
        long j = i - NX; src = wv; so = j;
        int row = (int)(j >> 8), c4 = (int)(j & 255);
        int orow = ((row >> 4) << 5) | (row & 15);
        dst = wcat; di = (long)orow * 256 + c4;
    } else if (i < NX + 2 * NW) {
        long j = i - NX - NW; src = wg; so = j;
        int row = (int)(j >> 8), c4 = (int)(j & 255);
        int orow = ((row >> 4) << 5) | 16 | (row & 15);
        dst = wcat; di = (long)orow * 256 + c4;
    } else {
        long j = i - NX - 2 * NW; src = wo; so = j; dst = wob; di = j;
    }
    const float4 v = ((const float4*)src)[so];
    ushort4 o;
    o.x = f32_to_bf16(v.x); o.y = f32_to_bf16(v.y);
    o.z = f32_to_bf16(v.z); o.w = f32_to_bf16(v.w);
    ((ushort4*)dst)[di] = o;
}

// ---------------- 256x256 stagger-pipelined GEMM (m201 wait discipline) ----------------
// BM=BN=256, 512 threads (8 waves, 2M x 4N), per-wave 128x64 via 16x16x32,
// acc[8][4]. K = 32 units of 32. LDS 128 KB = ring of 4 unit-slots (A 16KB +
// B 16KB), fragment-tiled 1KB lane-linear frags (0 conflicts, linear
// gload_lds dest; layout refcheck'd r1/r2). Stage-ahead 3 units.
// KEY (r2 post-mortem): ds_reads ISSUE before the pre-MFMA barrier but are
// NOT drained there -- no lgkmcnt(0); the compiler's counted lgkm waits land
// after the barrier, just before each MFMA use. While a wave waits on its
// reads its SIMD-sibling computes (the m201 stagger mechanism r2's
// drain-before-barrier destroyed). Single sched_barrier(0) per unit (before
// the end-of-unit barrier) pins unit-u reads before slot reuse; the vmcnt
// asm's memory clobber blocks illegal hoists. vmcnt(8) counted, never 0
// until the 8->4->0 drain.
// EPI=0: silu-gate on interleaved v/g frag pairs -> gated bf16 [M,1024]
// EPI=1: +bf16 residual -> pre bf16 [M,1024] (in-place over Xb is safe)
template<int EPI>
__global__ __launch_bounds__(512, 2) void gemmS(
    const ushort_t* __restrict__ A,
    const ushort_t* __restrict__ Bm,
    const ushort_t* __restrict__ Xb,
    ushort_t* __restrict__ out,
    int nbs)                          // log2(n-blocks per XCD stripe)
{
    extern __shared__ ushort_t lds[];   // 65536 ushorts = 128 KB, 4 slots x 16384

    const int flat = blockIdx.x;
    const int xcd  = flat & 7;
    const int ii   = flat >> 3;
    const int m0   = ((xcd << 3) + (ii >> nbs)) << 8;
    const int n0   = (ii & ((1 << nbs) - 1)) << 8;

    const int tid  = threadIdx.x;
    const int w    = tid >> 6;         // wave 0..7
    const int l    = tid & 63;
    const int wm   = w >> 2;           // 0..1 (M)
    const int wn   = w & 3;            // 0..3 (N)
    const int fr   = l & 15;
    const int quad = l >> 4;

    f32x4 acc[8][4];
    const f32x4 vzero = {0.f, 0.f, 0.f, 0.f};
#pragma unroll
    for (int i = 0; i < 8; ++i)
#pragma unroll
        for (int j = 0; j < 4; ++j) acc[i][j] = vzero;

    // staging: wave w owns A frags {w, w+8} (rows m0+w*16+fr / +128) and
    // B frags {w, w+8}; lane k-chunk = quad*8 within the unit's K=32.
    const long sA0 = (long)(m0 + w * 16 + fr) * DM + (quad << 3);
    const long sA1 = sA0 + 128 * (long)DM;
    const long sB0 = (long)(n0 + w * 16 + fr) * DM + (quad << 3);
    const long sB1 = sB0 + 128 * (long)DM;

    auto stageA = [&](int u) {
        const int d  = (u & 3) * 16384 + w * 512;
        const int ko = u * 32;
        gload16(A + sA0 + ko, lds + d);
        gload16(A + sA1 + ko, lds + d + 4096);
    };
    auto stageB = [&](int u) {
        const int d  = (u & 3) * 16384 + 8192 + w * 512;
        const int ko = u * 32;
        gload16(Bm + sB0 + ko, lds + d);
        gload16(Bm + sB1 + ko, lds + d + 4096);
    };

    // fragment read bases (slot-relative, ushorts)
    const int rA = wm * 4096 + l * 8;          // + slot*16384 + i*512
    const int rB = 8192 + wn * 2048 + l * 8;   // + slot*16384 + j*512

    // prologue: units 0,1,2 in flight (12 wave-loads); unit 0 landed
    stageA(0); stageB(0);
    stageA(1); stageB(1);
    stageA(2); stageB(2);
    asm volatile("s_waitcnt vmcnt(8)" ::: "memory");
    __builtin_amdgcn_s_barrier();

    for (int u = 0; u < 32; ++u) {
        const int sb = (u & 3) * 16384;
        bf16x8 af[4], bf[4];

        // ---- phase A: frags i=0..3 x j=0..3 (8 ds_reads, no drain) ----
#pragma unroll
        for (int j = 0; j < 4; ++j) bf[j] = *(const bf16x8*)(lds + sb + rB + j * 512);
#pragma unroll
        for (int i = 0; i < 4; ++i) af[i] = *(const bf16x8*)(lds + sb + rA + i * 512);
        if (u < 29) stageA(u + 3);
        __builtin_amdgcn_s_barrier();
        __builtin_amdgcn_s_setprio(1);
#pragma unroll
        for (int j = 0; j < 4; ++j)
#pragma unroll
            for (int i = 0; i < 4; ++i)
                acc[i][j] = __builtin_amdgcn_mfma_f32_16x16x32_bf16(
                    af[i], bf[j], acc[i][j], 0, 0, 0);
        __builtin_amdgcn_s_setprio(0);
        __builtin_amdgcn_s_barrier();

        // ---- phase B: frags i=4..7 x j=0..3 (4 ds_reads, bf reused) ----
#pragma unroll
        for (int i = 0; i < 4; ++i) af[i] = *(const bf16x8*)(lds + sb + rA + (4 + i) * 512);
        if (u < 29) stageB(u + 3);
        __builtin_amdgcn_s_barrier();
        __builtin_amdgcn_s_setprio(1);
#pragma unroll
        for (int j = 0; j < 4; ++j)
#pragma unroll
            for (int i = 0; i < 4; ++i)
                acc[4 + i][j] = __builtin_amdgcn_mfma_f32_16x16x32_bf16(
                    af[i], bf[j], acc[4 + i][j], 0, 0, 0);
        __builtin_amdgcn_s_setprio(0);
        // counted vmcnt: guarantee unit u+1 landed before its reads issue
        if (u < 29)       { asm volatile("s_waitcnt vmcnt(8)" ::: "memory"); }
        else if (u == 29) { asm volatile("s_waitcnt vmcnt(4)" ::: "memory"); }
        else if (u == 30) { asm volatile("s_waitcnt vmcnt(0)" ::: "memory"); }
        __builtin_amdgcn_sched_barrier(0);   // pin unit-u reads before slot reuse
        __builtin_amdgcn_s_barrier();
    }

    // epilogue; C/D layout: col = lane&15, row = quad*4 + r (refcheck'd r1/r2)
    const int rowb = m0 + wm * 128;
    const int colb = n0 + wn * 64;
    if (EPI == 0) {
        // interleaved cat-cols: even frag = v, odd frag = g (same 16 v-cols)
#pragma unroll
        for (int i = 0; i < 8; ++i)
#pragma unroll
            for (int jp = 0; jp < 2; ++jp) {
                const int cb   = colb + jp * 32;
                const int vcol = ((cb >> 5) << 4) + fr;
#pragma unroll
                for (int r = 0; r < 4; ++r) {
                    const int row = rowb + i * 16 + quad * 4 + r;
                    float v = acc[i][2 * jp][r];
                    float g = acc[i][2 * jp + 1][r];
                    float gate = g / (1.0f + __expf(-g));   // silu
                    out[(long)row * DM + vcol] = f32_to_bf16(v * gate);
                }
            }
    } else {
#pragma unroll
        for (int i = 0; i < 8; ++i)
#pragma unroll
            for (int j = 0; j < 4; ++j) {
                const int col = colb + j * 16 + fr;
#pragma unroll
                for (int r = 0; r < 4; ++r) {
                    const int row = rowb + i * 16 + quad * 4 + r;
                    float pre = acc[i][j][r] + bf16_to_f32(Xb[(long)row * DM + col]);
                    out[(long)row * DM + col] = f32_to_bf16(pre);
                }
            }
    }
}

// ---------------- LayerNorm over rows of 1024 ----------------
__global__ __launch_bounds__(256) void ln_rows(const ushort_t* __restrict__ pre,
                                               const float* __restrict__ gamma,
                                               const float* __restrict__ beta,
                                               float* __restrict__ out)
{
    const int row = blockIdx.x;
    const int tid = threadIdx.x;
    const int wave = tid >> 6, lane = tid & 63;

    ushort4 u = ((const ushort4*)(pre + row * DM))[tid];
    float p0 = bf16_to_f32(u.x), p1 = bf16_to_f32(u.y);
    float p2 = bf16_to_f32(u.z), p3 = bf16_to_f32(u.w);

    float s  = p0 + p1 + p2 + p3;
    float ss = p0 * p0 + p1 * p1 + p2 * p2 + p3 * p3;
#pragma unroll
    for (int off = 32; off > 0; off >>= 1) {
        s  += __shfl_down(s, off);
        ss += __shfl_down(ss, off);
    }
    __shared__ float red[8];
    __shared__ float mb[2];
    if (lane == 0) { red[wave] = s; red[4 + wave] = ss; }
    __syncthreads();
    if (tid == 0) {
        float S  = red[0] + red[1] + red[2] + red[3];
        float SS = red[4] + red[5] + red[6] + red[7];
        float mean = S * (1.0f / 1024.0f);
        float var  = SS * (1.0f / 1024.0f) - mean * mean;
        mb[0] = mean;
        mb[1] = rsqrtf(var + 1e-5f);
    }
    __syncthreads();
    const float mean = mb[0], rs = mb[1];

    float4 gm = ((const float4*)gamma)[tid];
    float4 bt = ((const float4*)beta)[tid];
    float4 o;
    o.x = (p0 - mean) * rs * gm.x + bt.x;
    o.y = (p1 - mean) * rs * gm.y + bt.y;
    o.z = (p2 - mean) * rs * gm.z + bt.z;
    o.w = (p3 - mean) * rs * gm.w + bt.w;
    ((float4*)(out + row * DM))[tid] = o;
}

// ---------------- launch ----------------
extern "C" void kernel_launch(void* const* d_in, const int* in_sizes, int n_in,
                              void* d_out, int out_size, void* d_ws, size_t ws_size,
                              hipStream_t stream) {
    // setup_inputs order: x, W_Q, W_K, W_V, W_g, W_alpha, W_O, ln_gamma, ln_beta
    const float* x     = (const float*)d_in[0];
    const float* WV    = (const float*)d_in[3];
    const float* WG    = (const float*)d_in[4];
    const float* WO    = (const float*)d_in[6];
    const float* gamma = (const float*)d_in[7];
    const float* beta  = (const float*)d_in[8];
    float* out = (float*)d_out;

    // ws layout: [0,32MB): x_bf16 (aliased as pre) | [32,64MB): gated
    //            [64,68MB): wcat (2048x1024 interleaved-16) | [68,70MB): wob
    char* ws = (char*)d_ws;
    ushort_t* xb    = (ushort_t*)ws;
    ushort_t* gated = (ushort_t*)(ws + (size_t)M_TOT * DM * 2);
    ushort_t* wcat  = (ushort_t*)(ws + (size_t)M_TOT * DM * 4);
    ushort_t* wob   = (ushort_t*)(ws + (size_t)M_TOT * DM * 4 + (size_t)2 * DM * DM * 2);
    ushort_t* pre   = xb;  // alias: in-place residual+store in gemmS<1>

    static bool attr_set = false;
    if (!attr_set) {
        hipFuncSetAttribute((const void*)&gemmS<0>,
                            hipFuncAttributeMaxDynamicSharedMemorySize, 131072);
        hipFuncSetAttribute((const void*)&gemmS<1>,
                            hipFuncAttributeMaxDynamicSharedMemorySize, 131072);
        attr_set = true;
    }

    const int nCvt = (M_TOT * DM + 3 * DM * DM) / 4 / 256;
    cvt_all<<<nCvt, 256, 0, stream>>>(x, WV, WG, WO, xb, wcat, wob);

    // V&g cat-GEMM: M=16384 (64 m-blocks), N_cat=2048 (8 n-blocks) -> 512
    gemmS<0><<<512, 512, 131072, stream>>>(xb, wcat, nullptr, gated, 3);
    // O-proj: M=16384 (64), N=1024 (4 n-blocks) -> 256
    gemmS<1><<<256, 512, 131072, stream>>>(gated, wob, xb, pre, 2);

    ln_rows<<<M_TOT, 256, 0, stream>>>(pre, gamma, beta, out);
}